// Round 1
// baseline (108.793 us; speedup 1.0000x reference)
//
#include <hip/hip_runtime.h>

typedef float v4f __attribute__((ext_vector_type(4)));

#define NTOK 512
#define EDIM 64
#define HDIM 128
#define NN   (NTOK*NTOK)

__device__ __forceinline__ float sigf(float x) {
    return __builtin_amdgcn_rcpf(1.f + __expf(-x));
}

// Kernel 1: per flat token row g (= b*512+n):
//   A[g][h] = X[g]·Wc1[0:64, h]
//   B[g][h] = X[g]·Wc1[64:128, h] + bc1[h]
//   out[b,n,n] = sigmoid( relu(X[g]·Ws1 + bs1) · Ws2 + bs2 )
__global__ __launch_bounds__(128) void precomp_kernel(
    const float* __restrict__ X, const float* __restrict__ Wc1, const float* __restrict__ bc1,
    const float* __restrict__ Ws1, const float* __restrict__ bs1,
    const float* __restrict__ Ws2, const float* __restrict__ bs2,
    float* __restrict__ Ag, float* __restrict__ Bg, float* __restrict__ out)
{
    __shared__ float Xs[8*EDIM];     // 8 token rows of X
    __shared__ float red[8*132];     // padded reduction buffer
    const int t  = threadIdx.x;      // h index, 0..127
    const int g0 = blockIdx.x * 8;   // first flat row

    for (int i = t; i < 8*EDIM; i += 128) Xs[i] = X[g0*EDIM + i];
    __syncthreads();

    float accA[8] = {0}, accB[8] = {0}, accS[8] = {0};
    #pragma unroll 8
    for (int e = 0; e < EDIM; e++) {
        float wt = Wc1[e*HDIM + t];
        float wb = Wc1[(EDIM+e)*HDIM + t];
        float ws = Ws1[e*HDIM + t];
        #pragma unroll
        for (int r = 0; r < 8; r++) {
            float x = Xs[r*EDIM + e];
            accA[r] = fmaf(x, wt, accA[r]);
            accB[r] = fmaf(x, wb, accB[r]);
            accS[r] = fmaf(x, ws, accS[r]);
        }
    }
    const float b1 = bc1[t], s1 = bs1[t], w2 = Ws2[t];
    #pragma unroll
    for (int r = 0; r < 8; r++) {
        Ag[(g0+r)*HDIM + t] = accA[r];
        Bg[(g0+r)*HDIM + t] = accB[r] + b1;
        float hd = fmaxf(accS[r] + s1, 0.f);
        red[r*132 + t] = hd * w2;
    }
    __syncthreads();
    if (t < 8) {
        const float* rr = red + t*132;
        float s = 0.f;
        #pragma unroll
        for (int i = 0; i < HDIM/4; i++) {
            v4f v = *(const v4f*)(rr + 4*i);
            s += v[0] + v[1] + v[2] + v[3];
        }
        float val = sigf(s + bs2[0]);
        int g = g0 + t;
        int b = g >> 9, n = g & 511;
        out[b*NN + n*NTOK + n] = val;
    }
}

// Kernel 2: 64x64 pair tile per block.
//   value(r,c) = sigmoid( sum_h relu(A[min][h] + B[max][h]) * Wc2[h] + bc2 )
// Upper tiles (tr<tc): Row=A[r-range], Col=B[c-range].
// Lower tiles (tr>tc): Row=B[r-range], Col=A[c-range]  (add commutes).
// Diag tiles: compute full, store r<c and its mirror; diagonal untouched.
// LDS layout (zero padding, 64KB total): element (k,h) at
//   k*128 + 4*((h>>2) ^ (k&31)) + (h&3)
// -> conflict-minimal b128 staging writes AND <=2-way b128 compute reads.
__global__ __launch_bounds__(256) void pair_kernel(
    const float* __restrict__ Ag, const float* __restrict__ Bg,
    const float* __restrict__ Wc2, const float* __restrict__ bc2,
    float* __restrict__ out)
{
    __shared__ float RowT[64*HDIM];
    __shared__ float ColT[64*HDIM];

    const int t  = threadIdx.x;
    const int tc = blockIdx.x, tr = blockIdx.y, b = blockIdx.z;
    const int r0 = tr*64, c0 = tc*64;

    const float* Rsrc;
    const float* Csrc;
    if (tr <= tc) { Rsrc = Ag + (b*NTOK + r0)*HDIM; Csrc = Bg + (b*NTOK + c0)*HDIM; }
    else          { Rsrc = Bg + (b*NTOK + r0)*HDIM; Csrc = Ag + (b*NTOK + c0)*HDIM; }

    // ---- stage (global float4 coalesced -> swizzled LDS b128) ----
    {
        const int hv = t & 31;            // float4 index along h
        for (int k = t >> 5; k < 64; k += 8) {
            const int sw = 4*(hv ^ (k & 31));
            *(v4f*)(RowT + k*HDIM + sw) = *(const v4f*)(Rsrc + k*HDIM + 4*hv);
            *(v4f*)(ColT + k*HDIM + sw) = *(const v4f*)(Csrc + k*HDIM + 4*hv);
        }
    }
    __syncthreads();

    // thread covers rows {ti+16u}, cols {4tj+v}
    const int ti = t & 15, tj = t >> 4;
    int rbase[4], rmask[4], cbase[4], cmask[4];
    #pragma unroll
    for (int u = 0; u < 4; u++) {
        int k = ti + 16*u; rbase[u] = k*HDIM; rmask[u] = k & 31;
        int c = 4*tj + u;  cbase[u] = c*HDIM; cmask[u] = c & 31;
    }

    v4f acc[4] = {{0,0,0,0},{0,0,0,0},{0,0,0,0},{0,0,0,0}};  // acc[u][v]
    for (int hq = 0; hq < HDIM/4; hq++) {
        const v4f w4 = *(const v4f*)(Wc2 + 4*hq);   // wave-uniform -> s_load
        v4f ra[4], cb[4];
        #pragma unroll
        for (int u = 0; u < 4; u++) ra[u] = *(const v4f*)(RowT + rbase[u] + 4*(hq ^ rmask[u]));
        #pragma unroll
        for (int v = 0; v < 4; v++) cb[v] = *(const v4f*)(ColT + cbase[v] + 4*(hq ^ cmask[v]));
        #pragma unroll
        for (int hh = 0; hh < 4; hh++) {
            #pragma unroll
            for (int u = 0; u < 4; u++) {
                #pragma unroll
                for (int v = 0; v < 4; v++) {
                    float s = fmaxf(ra[u][hh] + cb[v][hh], 0.f);
                    acc[u][v] = fmaf(s, w4[hh], acc[u][v]);
                }
            }
        }
    }

    const float bb   = bc2[0];
    const int obase  = b*NN;
    if (tr == tc) {
        #pragma unroll
        for (int u = 0; u < 4; u++) {
            const int r = r0 + ti + 16*u;
            #pragma unroll
            for (int v = 0; v < 4; v++) {
                const int c = c0 + 4*tj + v;
                if (r < c) {
                    float s = sigf(acc[u][v] + bb);
                    out[obase + r*NTOK + c] = s;
                    out[obase + c*NTOK + r] = s;
                }
            }
        }
    } else {
        #pragma unroll
        for (int u = 0; u < 4; u++) {
            const int r = r0 + ti + 16*u;
            v4f sv;
            #pragma unroll
            for (int v = 0; v < 4; v++) sv[v] = sigf(acc[u][v] + bb);
            *(v4f*)(out + obase + r*NTOK + c0 + 4*tj) = sv;
        }
    }
}

extern "C" void kernel_launch(void* const* d_in, const int* in_sizes, int n_in,
                              void* d_out, int out_size, void* d_ws, size_t ws_size,
                              hipStream_t stream) {
    const float* X   = (const float*)d_in[0];
    const float* Wc1 = (const float*)d_in[1];
    const float* bc1 = (const float*)d_in[2];
    const float* Wc2 = (const float*)d_in[3];
    const float* bc2 = (const float*)d_in[4];
    const float* Ws1 = (const float*)d_in[5];
    const float* bs1 = (const float*)d_in[6];
    const float* Ws2 = (const float*)d_in[7];
    const float* bs2 = (const float*)d_in[8];
    float* out = (float*)d_out;

    float* Ag = (float*)d_ws;                 // 8*512*128 fp32 = 2 MB
    float* Bg = Ag + 8*NTOK*HDIM;             // 2 MB

    precomp_kernel<<<dim3(4096/8), dim3(128), 0, stream>>>(X, Wc1, bc1, Ws1, bs1, Ws2, bs2, Ag, Bg, out);
    pair_kernel<<<dim3(8, 8, 8), dim3(256), 0, stream>>>(Ag, Bg, Wc2, bc2, out);
}

// Round 2
// 104.478 us; speedup vs baseline: 1.0413x; 1.0413x over previous
//
#include <hip/hip_runtime.h>

typedef float v4f __attribute__((ext_vector_type(4)));
typedef float v2f __attribute__((ext_vector_type(2)));

#define NTOK 512
#define EDIM 64
#define HDIM 128
#define NN   (NTOK*NTOK)

__device__ __forceinline__ float sigf(float x) {
    return __builtin_amdgcn_rcpf(1.f + __expf(-x));
}

// Kernel 1: per flat token row g (= b*512+n):
//   A[g][h] = X[g]·Wc1[0:64, h]
//   B[g][h] = X[g]·Wc1[64:128, h] + bc1[h]
//   out[b,n,n] = sigmoid( relu(X[g]·Ws1 + bs1) · Ws2 + bs2 )
__global__ __launch_bounds__(128) void precomp_kernel(
    const float* __restrict__ X, const float* __restrict__ Wc1, const float* __restrict__ bc1,
    const float* __restrict__ Ws1, const float* __restrict__ bs1,
    const float* __restrict__ Ws2, const float* __restrict__ bs2,
    float* __restrict__ Ag, float* __restrict__ Bg, float* __restrict__ out)
{
    __shared__ float Xs[8*EDIM];     // 8 token rows of X
    __shared__ float red[8*132];     // padded reduction buffer
    const int t  = threadIdx.x;      // h index, 0..127
    const int g0 = blockIdx.x * 8;   // first flat row

    for (int i = t; i < 8*EDIM; i += 128) Xs[i] = X[g0*EDIM + i];
    __syncthreads();

    float accA[8] = {0}, accB[8] = {0}, accS[8] = {0};
    #pragma unroll 8
    for (int e = 0; e < EDIM; e++) {
        float wt = Wc1[e*HDIM + t];
        float wb = Wc1[(EDIM+e)*HDIM + t];
        float ws = Ws1[e*HDIM + t];
        #pragma unroll
        for (int r = 0; r < 8; r++) {
            float x = Xs[r*EDIM + e];
            accA[r] = fmaf(x, wt, accA[r]);
            accB[r] = fmaf(x, wb, accB[r]);
            accS[r] = fmaf(x, ws, accS[r]);
        }
    }
    const float b1 = bc1[t], s1 = bs1[t], w2 = Ws2[t];
    #pragma unroll
    for (int r = 0; r < 8; r++) {
        Ag[(g0+r)*HDIM + t] = accA[r];
        Bg[(g0+r)*HDIM + t] = accB[r] + b1;
        float hd = fmaxf(accS[r] + s1, 0.f);
        red[r*132 + t] = hd * w2;
    }
    __syncthreads();
    if (t < 8) {
        const float* rr = red + t*132;
        float s = 0.f;
        #pragma unroll
        for (int i = 0; i < HDIM/4; i++) {
            v4f v = *(const v4f*)(rr + 4*i);
            s += v[0] + v[1] + v[2] + v[3];
        }
        float val = sigf(s + bs2[0]);
        int g = g0 + t;
        int b = g >> 9, n = g & 511;
        out[b*NN + n*NTOK + n] = val;
    }
}

// Kernel 2: upper-triangle-only half-tiles (64 rows x 32 cols), mirror via LDS transpose.
// Work units per batch: u in [0,72):
//   u<56:  off-diag pair p=u>>1 -> (tr,tc) tr<tc; half=u&1 selects 32-col half
//   u>=56: diag tile d=(u-56)>>1, half=(u-56)&1; compute full rect, store only r<c (+mirror)
// value(r,c), r<c:  sigmoid( sum_h relu(A[r][h] + B[c][h]) * Wc2[h] + bc2 )
// LDS swizzle (zero padding): element (k,h) at k*128 + 4*((h>>2)^(k&31)) + (h&3)
__global__ __launch_bounds__(256) void pair_kernel(
    const float* __restrict__ Ag, const float* __restrict__ Bg,
    const float* __restrict__ Wc2, const float* __restrict__ bc2,
    float* __restrict__ out)
{
    __shared__ float RowT[64*HDIM];   // 32 KB
    __shared__ float ColT[32*HDIM];   // 16 KB (reused as transpose buffer after loop)
    __shared__ float WcS[HDIM];       // 512 B

    const int t = threadIdx.x;
    const int b = blockIdx.y;
    const int u = blockIdx.x;         // 0..71
    int tr, tc, half;
    if (u < 56) {
        int p = u >> 1; half = u & 1;
        tr = 0; int rem = p;
        while (rem >= 7 - tr) { rem -= 7 - tr; tr++; }
        tc = tr + 1 + rem;
    } else {
        int d = (u - 56) >> 1; half = u & 1; tr = d; tc = d;
    }
    const int r0 = tr*64, c0 = tc*64 + half*32;
    const bool isdiag = (tr == tc);

    const float* Rsrc = Ag + (b*NTOK + r0)*HDIM;
    const float* Csrc = Bg + (b*NTOK + c0)*HDIM;

    if (t < 32) *(v4f*)(WcS + 4*t) = *(const v4f*)(Wc2 + 4*t);
    {
        const int hv = t & 31;        // float4 index along h
        for (int k = t >> 5; k < 64; k += 8) {
            const int sw = 4*(hv ^ (k & 31));
            *(v4f*)(RowT + k*HDIM + sw) = *(const v4f*)(Rsrc + k*HDIM + 4*hv);
        }
        for (int k = t >> 5; k < 32; k += 8) {
            const int sw = 4*(hv ^ k);
            *(v4f*)(ColT + k*HDIM + sw) = *(const v4f*)(Csrc + k*HDIM + 4*hv);
        }
    }
    __syncthreads();

    // thread covers rows {ti+16u}, cols {2tj+v}; consecutive lanes -> consecutive cols
    const int tj = t & 15, ti = t >> 4;
    int rbase[4], rmask[4];
    #pragma unroll
    for (int uu = 0; uu < 4; uu++) { int k = ti + 16*uu; rbase[uu] = k*HDIM; rmask[uu] = k & 31; }
    int cbase[2], cmask[2];
    #pragma unroll
    for (int v = 0; v < 2; v++) { int c = 2*tj + v; cbase[v] = c*HDIM; cmask[v] = c & 31; }

    float acc[4][2] = {};
    for (int hq = 0; hq < HDIM/4; hq++) {
        const v4f w4 = *(const v4f*)(WcS + 4*hq);   // LDS broadcast, no global latency
        v4f ra[4], cb[2];
        #pragma unroll
        for (int uu = 0; uu < 4; uu++) ra[uu] = *(const v4f*)(RowT + rbase[uu] + 4*(hq ^ rmask[uu]));
        #pragma unroll
        for (int v = 0; v < 2; v++)   cb[v]  = *(const v4f*)(ColT + cbase[v] + 4*(hq ^ cmask[v]));
        #pragma unroll
        for (int hh = 0; hh < 4; hh++) {
            #pragma unroll
            for (int uu = 0; uu < 4; uu++) {
                #pragma unroll
                for (int v = 0; v < 2; v++) {
                    float s = fmaxf(ra[uu][hh] + cb[v][hh], 0.f);
                    acc[uu][v] = fmaf(s, w4[hh], acc[uu][v]);
                }
            }
        }
    }

    const float bb = bc2[0];
    float* outb = out + b*NN;
    float sv[4][2];
    #pragma unroll
    for (int uu = 0; uu < 4; uu++)
        #pragma unroll
        for (int v = 0; v < 2; v++) sv[uu][v] = sigf(acc[uu][v] + bb);

    if (!isdiag) {
        // direct store: rows r0+ti+16uu, cols c0+2tj+{0,1} -> contiguous float2 lines
        #pragma unroll
        for (int uu = 0; uu < 4; uu++) {
            int r = r0 + ti + 16*uu;
            v2f p; p[0] = sv[uu][0]; p[1] = sv[uu][1];
            *(v2f*)(outb + r*NTOK + c0 + 2*tj) = p;
        }
        // mirror via LDS transpose (reuse ColT; stride 68 keeps 16B alignment)
        __syncthreads();
        float* Tb = ColT;
        #pragma unroll
        for (int uu = 0; uu < 4; uu++)
            #pragma unroll
            for (int v = 0; v < 2; v++)
                Tb[(2*tj + v)*68 + ti + 16*uu] = sv[uu][v];
        __syncthreads();
        const int q = t >> 3, x0 = (t & 7) * 8;   // 32 rows x 64 cols readout
        const float* src = Tb + q*68 + x0;
        v4f a0 = *(const v4f*)src;
        v4f a1 = *(const v4f*)(src + 4);
        float* drow = outb + (c0 + q)*NTOK + r0 + x0;
        *(v4f*)drow = a0;
        *(v4f*)(drow + 4) = a1;
    } else {
        // diag half-tile: store only r<c, plus mirror; diagonal itself from precomp
        #pragma unroll
        for (int uu = 0; uu < 4; uu++) {
            int r = r0 + ti + 16*uu;
            #pragma unroll
            for (int v = 0; v < 2; v++) {
                int c = c0 + 2*tj + v;
                if (r < c) {
                    outb[r*NTOK + c] = sv[uu][v];
                    outb[c*NTOK + r] = sv[uu][v];
                }
            }
        }
    }
}

extern "C" void kernel_launch(void* const* d_in, const int* in_sizes, int n_in,
                              void* d_out, int out_size, void* d_ws, size_t ws_size,
                              hipStream_t stream) {
    const float* X   = (const float*)d_in[0];
    const float* Wc1 = (const float*)d_in[1];
    const float* bc1 = (const float*)d_in[2];
    const float* Wc2 = (const float*)d_in[3];
    const float* bc2 = (const float*)d_in[4];
    const float* Ws1 = (const float*)d_in[5];
    const float* bs1 = (const float*)d_in[6];
    const float* Ws2 = (const float*)d_in[7];
    const float* bs2 = (const float*)d_in[8];
    float* out = (float*)d_out;

    float* Ag = (float*)d_ws;                 // 4096*128 fp32 = 2 MB
    float* Bg = Ag + 8*NTOK*HDIM;             // 2 MB

    precomp_kernel<<<dim3(4096/8), dim3(128), 0, stream>>>(X, Wc1, bc1, Ws1, bs1, Ws2, bs2, Ag, Bg, out);
    pair_kernel<<<dim3(72, 8), dim3(256), 0, stream>>>(Ag, Bg, Wc2, bc2, out);
}

// Round 3
// 103.444 us; speedup vs baseline: 1.0517x; 1.0100x over previous
//
#include <hip/hip_runtime.h>

typedef float v4f __attribute__((ext_vector_type(4)));
typedef float v2f __attribute__((ext_vector_type(2)));

#define NTOK 512
#define EDIM 64
#define HDIM 128
#define NN   (NTOK*NTOK)
#define CPAD 36

__device__ __forceinline__ float sigf(float x) {
    return __builtin_amdgcn_rcpf(1.f + __expf(-x));
}

// Kernel 1: per flat token row g (= b*512+n):
//   A[g][h] = X[g]·Wc1[0:64, h]
//   B[g][h] = X[g]·Wc1[64:128, h] + bc1[h]
//   out[b,n,n] = sigmoid( relu(X[g]·Ws1 + bs1) · Ws2 + bs2 )
__global__ __launch_bounds__(128) void precomp_kernel(
    const float* __restrict__ X, const float* __restrict__ Wc1, const float* __restrict__ bc1,
    const float* __restrict__ Ws1, const float* __restrict__ bs1,
    const float* __restrict__ Ws2, const float* __restrict__ bs2,
    float* __restrict__ Ag, float* __restrict__ Bg, float* __restrict__ out)
{
    __shared__ float Xs[8*EDIM];
    __shared__ float red[8*132];
    const int t  = threadIdx.x;      // h index, 0..127
    const int g0 = blockIdx.x * 8;   // first flat row

    for (int i = t; i < 8*EDIM; i += 128) Xs[i] = X[g0*EDIM + i];
    __syncthreads();

    float accA[8] = {0}, accB[8] = {0}, accS[8] = {0};
    #pragma unroll 8
    for (int e = 0; e < EDIM; e++) {
        float wt = Wc1[e*HDIM + t];
        float wb = Wc1[(EDIM+e)*HDIM + t];
        float ws = Ws1[e*HDIM + t];
        #pragma unroll
        for (int r = 0; r < 8; r++) {
            float x = Xs[r*EDIM + e];
            accA[r] = fmaf(x, wt, accA[r]);
            accB[r] = fmaf(x, wb, accB[r]);
            accS[r] = fmaf(x, ws, accS[r]);
        }
    }
    const float b1 = bc1[t], s1 = bs1[t], w2 = Ws2[t];
    #pragma unroll
    for (int r = 0; r < 8; r++) {
        Ag[(g0+r)*HDIM + t] = accA[r];
        Bg[(g0+r)*HDIM + t] = accB[r] + b1;
        float hd = fmaxf(accS[r] + s1, 0.f);
        red[r*132 + t] = hd * w2;
    }
    __syncthreads();
    if (t < 8) {
        const float* rr = red + t*132;
        float s = 0.f;
        #pragma unroll
        for (int i = 0; i < HDIM/4; i++) {
            v4f v = *(const v4f*)(rr + 4*i);
            s += v[0] + v[1] + v[2] + v[3];
        }
        float val = sigf(s + bs2[0]);
        int g = g0 + t;
        int b = g >> 9, n = g & 511;
        out[b*NN + n*NTOK + n] = val;
    }
}

// Kernel 2: 64x32 half-tiles of the upper triangle, mirror via LDS transpose.
// Wave footprint = 32 rows x 16 cols (square-ish) to halve LDS bytes/flop.
// RowT: swizzled [k][h]: elem (k,h) at k*128 + 4*((h>>2)^(k&31)) + (h&3)
// ColT: transposed [h][c], pad CPAD=36 -> conflict-free b128 col reads.
// Inner math in float2 -> v_pk_add/v_pk_fma packed fp32.
__global__ __launch_bounds__(256) void pair_kernel(
    const float* __restrict__ Ag, const float* __restrict__ Bg,
    const float* __restrict__ Wc2, const float* __restrict__ bc2,
    float* __restrict__ out)
{
    __shared__ float RowT[64*HDIM];      // 32 KB
    __shared__ float ColT[HDIM*CPAD];    // 18 KB; reused as transpose buf (needs 8.5 KB)

    const int t = threadIdx.x;
    const int b = blockIdx.y;
    const int u = blockIdx.x;            // 0..71
    int tr, tc, half;
    if (u < 56) {
        int p = u >> 1; half = u & 1;
        tr = 0; int rem = p;
        while (rem >= 7 - tr) { rem -= 7 - tr; tr++; }
        tc = tr + 1 + rem;
    } else {
        int d = (u - 56) >> 1; half = u & 1; tr = d; tc = d;
    }
    const int r0 = tr*64, c0 = tc*64 + half*32;
    const bool isdiag = (tr == tc);

    const float* Rsrc = Ag + (b*NTOK + r0)*HDIM;
    const float* Csrc = Bg + (b*NTOK + c0)*HDIM;

    // ---- stage ----
    {
        const int hv = t & 31;
        for (int k = t >> 5; k < 64; k += 8) {
            const int sw = 4*(hv ^ (k & 31));
            *(v4f*)(RowT + k*HDIM + sw) = *(const v4f*)(Rsrc + k*HDIM + 4*hv);
        }
        for (int c = t >> 5; c < 32; c += 8) {
            #pragma unroll
            for (int e = 0; e < 4; e++) {
                int h = hv + 32*e;
                ColT[h*CPAD + c] = Csrc[c*HDIM + h];   // 4-way write conflict, 16 writes only
            }
        }
    }
    __syncthreads();

    // wave w: rows 32*(w&1)+[0,32), cols 16*(w>>1)+[0,16)
    const int w  = t >> 6;
    const int wr = w & 1, wc = w >> 1;
    const int l  = t & 63;
    const int ri = l & 15, cj = l >> 4;
    const int row0 = 32*wr + ri;            // thread rows row0, row0+16
    const int ccol = 16*wc + 4*cj;          // thread cols ccol..ccol+3

    const int rb0 = row0*HDIM,      rm0 = row0 & 31;
    const int rb1 = (row0+16)*HDIM, rm1 = (row0+16) & 31;

    v2f acc[2][2] = {{{0,0},{0,0}},{{0,0},{0,0}}};   // [row][colpair]
    for (int hq = 0; hq < HDIM/4; hq++) {
        const v4f w4 = *(const v4f*)(Wc2 + 4*hq);    // uniform -> s_load
        v4f ra0 = *(const v4f*)(RowT + rb0 + 4*(hq ^ rm0));
        v4f ra1 = *(const v4f*)(RowT + rb1 + 4*(hq ^ rm1));
        #pragma unroll
        for (int hh = 0; hh < 4; hh++) {
            const v4f cb = *(const v4f*)(ColT + (4*hq+hh)*CPAD + ccol);
            v2f clo; clo[0] = cb[0]; clo[1] = cb[1];
            v2f chi; chi[0] = cb[2]; chi[1] = cb[3];
            const float wv = w4[hh];
            v2f wv2; wv2[0] = wv; wv2[1] = wv;
            v2f z = {0.f, 0.f};
            {
                v2f a2; a2[0] = ra0[hh]; a2[1] = ra0[hh];
                v2f y0 = __builtin_elementwise_max(a2 + clo, z);
                v2f y1 = __builtin_elementwise_max(a2 + chi, z);
                acc[0][0] += y0 * wv2;
                acc[0][1] += y1 * wv2;
            }
            {
                v2f a2; a2[0] = ra1[hh]; a2[1] = ra1[hh];
                v2f y0 = __builtin_elementwise_max(a2 + clo, z);
                v2f y1 = __builtin_elementwise_max(a2 + chi, z);
                acc[1][0] += y0 * wv2;
                acc[1][1] += y1 * wv2;
            }
        }
    }

    const float bb = bc2[0];
    float* outb = out + b*NN;
    float sv[2][4];
    #pragma unroll
    for (int uu = 0; uu < 2; uu++) {
        sv[uu][0] = sigf(acc[uu][0][0] + bb);
        sv[uu][1] = sigf(acc[uu][0][1] + bb);
        sv[uu][2] = sigf(acc[uu][1][0] + bb);
        sv[uu][3] = sigf(acc[uu][1][1] + bb);
    }

    if (!isdiag) {
        // direct store: full float4 line per row
        #pragma unroll
        for (int uu = 0; uu < 2; uu++) {
            int r = r0 + row0 + 16*uu;
            v4f p; p[0] = sv[uu][0]; p[1] = sv[uu][1]; p[2] = sv[uu][2]; p[3] = sv[uu][3];
            *(v4f*)(outb + r*NTOK + c0 + ccol) = p;
        }
        // mirror via LDS transpose (reuse ColT; stride 68 keeps 16B alignment)
        __syncthreads();
        float* Tb = ColT;
        #pragma unroll
        for (int uu = 0; uu < 2; uu++)
            #pragma unroll
            for (int v = 0; v < 4; v++)
                Tb[(ccol + v)*68 + row0 + 16*uu] = sv[uu][v];
        __syncthreads();
        const int q = t >> 3, x0 = (t & 7) * 8;   // 32 rows x 64 cols readout
        const float* src = Tb + q*68 + x0;
        v4f a0 = *(const v4f*)src;
        v4f a1 = *(const v4f*)(src + 4);
        float* drow = outb + (c0 + q)*NTOK + r0 + x0;
        *(v4f*)drow = a0;
        *(v4f*)(drow + 4) = a1;
    } else {
        // diag half-tile: store only r<c, plus mirror; diagonal itself from precomp
        #pragma unroll
        for (int uu = 0; uu < 2; uu++) {
            int r = r0 + row0 + 16*uu;
            #pragma unroll
            for (int v = 0; v < 4; v++) {
                int c = c0 + ccol + v;
                if (r < c) {
                    outb[r*NTOK + c] = sv[uu][v];
                    outb[c*NTOK + r] = sv[uu][v];
                }
            }
        }
    }
}

extern "C" void kernel_launch(void* const* d_in, const int* in_sizes, int n_in,
                              void* d_out, int out_size, void* d_ws, size_t ws_size,
                              hipStream_t stream) {
    const float* X   = (const float*)d_in[0];
    const float* Wc1 = (const float*)d_in[1];
    const float* bc1 = (const float*)d_in[2];
    const float* Wc2 = (const float*)d_in[3];
    const float* bc2 = (const float*)d_in[4];
    const float* Ws1 = (const float*)d_in[5];
    const float* bs1 = (const float*)d_in[6];
    const float* Ws2 = (const float*)d_in[7];
    const float* bs2 = (const float*)d_in[8];
    float* out = (float*)d_out;

    float* Ag = (float*)d_ws;                 // 4096*128 fp32 = 2 MB
    float* Bg = Ag + 8*NTOK*HDIM;             // 2 MB

    precomp_kernel<<<dim3(4096/8), dim3(128), 0, stream>>>(X, Wc1, bc1, Ws1, bs1, Ws2, bs2, Ag, Bg, out);
    pair_kernel<<<dim3(72, 8), dim3(256), 0, stream>>>(Ag, Bg, Wc2, bc2, out);
}